// Round 18
// baseline (62.626 us; speedup 1.0000x reference)
//
#include <hip/hip_runtime.h>

#define NBLK 8192
#define C1f 0.92387953251128674f
#define S1f 0.38268343236508978f
#define R2f 0.70710678118654752f
#define TWO_PI 6.28318530717958648f

// word-level (4B/complex) bank swizzle: XOR bits [4:2] with bits [9:7].
// Enumerated: pass-A writes 2-way, pass-B r/w 2-way (all q), final uint4
// reads at the 8-lane/4-bank-span bandwidth floor. All conflict-optimal.
#define WIDX(c) ((c) ^ ((((c) >> 7) & 7) << 2))

typedef float cf __attribute__((ext_vector_type(2)));

__device__ __forceinline__ cf mkcf(float a, float b){ cf r; r.x = a; r.y = b; return r; }

// pack complex -> 2xbf16 in one u32 (lo = re, hi = im)
__device__ __forceinline__ unsigned pkbf(cf a){
    unsigned r;
    asm("v_cvt_pk_bf16_f32 %0, %1, %2" : "=v"(r) : "v"(a.x), "v"(a.y));
    return r;
}
// unpack u32 (2xbf16) -> complex
__device__ __forceinline__ cf unbf(unsigned u){
    return mkcf(__uint_as_float(u << 16), __uint_as_float(u & 0xffff0000u));
}

// ---------- VOP3P packed-f32 helpers ----------
__device__ __forceinline__ cf pk_add(cf a, cf b){
    cf r; asm("v_pk_add_f32 %0, %1, %2" : "=v"(r) : "v"(a), "v"(b)); return r;
}
__device__ __forceinline__ cf pk_sub(cf a, cf b){
    cf r; asm("v_pk_add_f32 %0, %1, %2 neg_lo:[0,1] neg_hi:[0,1]" : "=v"(r) : "v"(a), "v"(b)); return r;
}
// a - i*b = (a.x + b.y, a.y - b.x)
__device__ __forceinline__ cf pk_mi(cf a, cf b){
    cf r; asm("v_pk_add_f32 %0, %1, %2 op_sel:[0,1] op_sel_hi:[1,0] neg_hi:[0,1]" : "=v"(r) : "v"(a), "v"(b)); return r;
}
// a + i*b = (a.x - b.y, a.y + b.x)
__device__ __forceinline__ cf pk_pi(cf a, cf b){
    cf r; asm("v_pk_add_f32 %0, %1, %2 op_sel:[0,1] op_sel_hi:[1,0] neg_lo:[0,1]" : "=v"(r) : "v"(a), "v"(b)); return r;
}
// (-i)*a = (a.y, -a.x)
__device__ __forceinline__ cf pk_ni(cf a){
    cf r; asm("v_pk_add_f32 %0, %1, 0 op_sel:[1,0] op_sel_hi:[0,0] neg_hi:[1,0]" : "=v"(r) : "v"(a)); return r;
}
// ReLU both halves (no v_pk_max_f32 on gfx950)
__device__ __forceinline__ cf relu2(cf a){
    return mkcf(fmaxf(a.x, 0.0f), fmaxf(a.y, 0.0f));
}
// complex multiply a*b, both runtime (VGPR)
__device__ __forceinline__ cf pk_cmul(cf a, cf b){
    cf t, r;
    asm("v_pk_mul_f32 %0, %1, %2 op_sel:[0,0] op_sel_hi:[0,1]"
        : "=v"(t) : "v"(a), "v"(b));
    asm("v_pk_fma_f32 %0, %1, %2, %3 op_sel:[1,1,0] op_sel_hi:[1,0,1] neg_lo:[1,0,0] neg_hi:[0,0,0]"
        : "=v"(r) : "v"(a), "v"(b), "v"(t));
    return r;
}
// complex multiply a*K, K compile-time -> SGPR pair
__device__ __forceinline__ cf pk_cmuls(cf a, cf b){
    cf t, r;
    asm("v_pk_mul_f32 %0, %1, %2 op_sel:[0,0] op_sel_hi:[0,1]"
        : "=v"(t) : "v"(a), "s"(b));
    asm("v_pk_fma_f32 %0, %1, %2, %3 op_sel:[1,1,0] op_sel_hi:[1,0,1] neg_lo:[1,0,0] neg_hi:[0,0,0]"
        : "=v"(r) : "v"(a), "s"(b), "v"(t));
    return r;
}

// in-register 16-point DFT (natural in/out), radix-4 DIF, packed ops, SGPR constants
__device__ __forceinline__ void fft16pk(cf v[16]) {
    const cf K1 = mkcf(C1f,-S1f), K2 = mkcf(R2f,-R2f), K3 = mkcf(S1f,-C1f),
             K6 = mkcf(-R2f,-R2f), K9 = mkcf(-C1f,S1f);
    cf y[16];
    #pragma unroll
    for (int j1 = 0; j1 < 4; ++j1) {
        cf a0 = v[j1], a1 = v[j1+4], a2 = v[j1+8], a3 = v[j1+12];
        cf s0 = pk_add(a0,a2), d0 = pk_sub(a0,a2);
        cf s1 = pk_add(a1,a3), d1 = pk_sub(a1,a3);
        cf b0 = pk_add(s0,s1);
        cf b1 = pk_mi(d0,d1);
        cf b2 = pk_sub(s0,s1);
        cf b3 = pk_pi(d0,d1);
        if (j1 == 0)      { y[0]=b0; y[4]=b1;              y[8]=b2;              y[12]=b3; }
        else if (j1 == 1) { y[1]=b0; y[5]=pk_cmuls(b1,K1); y[9]=pk_cmuls(b2,K2); y[13]=pk_cmuls(b3,K3); }
        else if (j1 == 2) { y[2]=b0; y[6]=pk_cmuls(b1,K2); y[10]=pk_ni(b2);      y[14]=pk_cmuls(b3,K6); }
        else              { y[3]=b0; y[7]=pk_cmuls(b1,K3); y[11]=pk_cmuls(b2,K6);y[15]=pk_cmuls(b3,K9); }
    }
    #pragma unroll
    for (int p1 = 0; p1 < 4; ++p1) {
        cf c0 = y[4*p1], c1v = y[4*p1+1], c2v = y[4*p1+2], c3v = y[4*p1+3];
        cf s0 = pk_add(c0,c2v), d0 = pk_sub(c0,c2v);
        cf s1 = pk_add(c1v,c3v), d1 = pk_sub(c1v,c3v);
        v[p1]    = pk_add(s0,s1);
        v[4+p1]  = pk_mi(d0,d1);
        v[8+p1]  = pk_sub(s0,s1);
        v[12+p1] = pk_pi(d0,d1);
    }
}

// 64-lane sum via DPP; valid in lane 63
__device__ __forceinline__ float wred(float x) {
    x += __int_as_float(__builtin_amdgcn_update_dpp(0, __float_as_int(x), 0x111, 0xf, 0xf, false));
    x += __int_as_float(__builtin_amdgcn_update_dpp(0, __float_as_int(x), 0x112, 0xf, 0xf, false));
    x += __int_as_float(__builtin_amdgcn_update_dpp(0, __float_as_int(x), 0x114, 0xf, 0xf, false));
    x += __int_as_float(__builtin_amdgcn_update_dpp(0, __float_as_int(x), 0x118, 0xf, 0xf, false));
    x += __int_as_float(__builtin_amdgcn_update_dpp(0, __float_as_int(x), 0x142, 0xa, 0xf, false));
    x += __int_as_float(__builtin_amdgcn_update_dpp(0, __float_as_int(x), 0x143, 0xc, 0xf, false));
    return x;
}

__global__ __launch_bounds__(256, 4)
void fftmlp_bf(const float* __restrict__ x, const float* __restrict__ w1,
               const float* __restrict__ w2, float* __restrict__ out) {
    __shared__ __align__(16) unsigned buf[4096];   // 16 KB: 1 complex = 2xbf16 = 4 B
    __shared__ float sred[40];
    const int t = threadIdx.x;
    const int b = blockIdx.x;
    const cf* __restrict__ xr  = (const cf*)x + (size_t)b * 4096;
    const cf* __restrict__ w1c = (const cf*)w1;
    const cf* __restrict__ w2c = (const cf*)w2;
    float sn, cs;

    // ---- pass A: global x*w1 -> fft16 over stride-256 -> twiddle -> LDS(bf16) ----
    {
        cf v[16];
        #pragma unroll
        for (int q = 0; q < 16; ++q)
            v[q] = pk_cmul(xr[t + 256*q], w1c[t + 256*q]);
        fft16pk(v);
        __sincosf(-TWO_PI * (float)t * (1.0f/4096.0f), &sn, &cs);
        cf w = mkcf(cs, sn);
        buf[WIDX(t)] = pkbf(v[0]);
        cf tw = w;
        #pragma unroll
        for (int p = 1; p < 16; ++p) {
            buf[WIDX(p*256 + t)] = pkbf(pk_cmul(v[p], tw));
            tw = pk_cmul(tw, w);
        }
    }
    __syncthreads();

    // ---- pass B: within 256-blocks, stride 16, twiddle W_256^jp, in place ----
    {
        const int p    = t >> 4;
        const int jp   = t & 15;
        const int base = p*256 + jp;
        cf u[16];
        #pragma unroll
        for (int q = 0; q < 16; ++q) u[q] = unbf(buf[WIDX(base + 16*q)]);
        fft16pk(u);
        __sincosf(-TWO_PI * (float)jp * (1.0f/256.0f), &sn, &cs);
        cf w = mkcf(cs, sn);
        buf[WIDX(base)] = pkbf(u[0]);
        cf tw = w;
        #pragma unroll
        for (int pp = 1; pp < 16; ++pp) {
            buf[WIDX(base + 16*pp)] = pkbf(pk_cmul(u[pp], tw));
            tw = pk_cmul(tw, w);
        }
    }
    __syncthreads();

    // ---- final: 4x uint4 (16 packed complexes), incremental F accumulation ----
    cf F0, F1, F2, F3;
    {
        const cf K1 = mkcf(C1f,-S1f), K2 = mkcf(R2f,-R2f), K3 = mkcf(S1f,-C1f),
                 K6 = mkcf(-R2f,-R2f), K9 = mkcf(-C1f,S1f);
        uint4 Q0 = *reinterpret_cast<const uint4*>(&buf[WIDX(16*t + 0)]);
        uint4 Q1 = *reinterpret_cast<const uint4*>(&buf[WIDX(16*t + 4)]);
        uint4 Q2 = *reinterpret_cast<const uint4*>(&buf[WIDX(16*t + 8)]);
        uint4 Q3 = *reinterpret_cast<const uint4*>(&buf[WIDX(16*t + 12)]);
        // za[j] = packed z[j]; z[bb], z[bb+4], z[bb+8], z[bb+12] feed batch bb
        const unsigned za[16] = {Q0.x,Q0.y,Q0.z,Q0.w, Q1.x,Q1.y,Q1.z,Q1.w,
                                 Q2.x,Q2.y,Q2.z,Q2.w, Q3.x,Q3.y,Q3.z,Q3.w};
        {   // bb = 0
            cf a0 = unbf(za[0]), a1 = unbf(za[4]), a2 = unbf(za[8]), a3 = unbf(za[12]);
            cf s0 = pk_add(a0,a2), d0 = pk_sub(a0,a2);
            cf s1 = pk_add(a1,a3), d1 = pk_sub(a1,a3);
            F0 = pk_add(s0,s1);
            F1 = pk_mi(d0,d1);
            F2 = pk_sub(s0,s1);
            F3 = pk_pi(d0,d1);
        }
        {   // bb = 1: multipliers 1,K1,K2,K3
            cf a0 = unbf(za[1]), a1 = unbf(za[5]), a2 = unbf(za[9]), a3 = unbf(za[13]);
            cf s0 = pk_add(a0,a2), d0 = pk_sub(a0,a2);
            cf s1 = pk_add(a1,a3), d1 = pk_sub(a1,a3);
            F0 = pk_add(F0, pk_add(s0,s1));
            F1 = pk_add(F1, pk_cmuls(pk_mi(d0,d1), K1));
            F2 = pk_add(F2, pk_cmuls(pk_sub(s0,s1), K2));
            F3 = pk_add(F3, pk_cmuls(pk_pi(d0,d1), K3));
        }
        {   // bb = 2: multipliers 1,K2,-i,K6
            cf a0 = unbf(za[2]), a1 = unbf(za[6]), a2 = unbf(za[10]), a3 = unbf(za[14]);
            cf s0 = pk_add(a0,a2), d0 = pk_sub(a0,a2);
            cf s1 = pk_add(a1,a3), d1 = pk_sub(a1,a3);
            F0 = pk_add(F0, pk_add(s0,s1));
            F1 = pk_add(F1, pk_cmuls(pk_mi(d0,d1), K2));
            F2 = pk_add(F2, pk_ni(pk_sub(s0,s1)));
            F3 = pk_add(F3, pk_cmuls(pk_pi(d0,d1), K6));
        }
        {   // bb = 3: multipliers 1,K3,K6,K9
            cf a0 = unbf(za[3]), a1 = unbf(za[7]), a2 = unbf(za[11]), a3 = unbf(za[15]);
            cf s0 = pk_add(a0,a2), d0 = pk_sub(a0,a2);
            cf s1 = pk_add(a1,a3), d1 = pk_sub(a1,a3);
            F0 = pk_add(F0, pk_add(s0,s1));
            F1 = pk_add(F1, pk_cmuls(pk_mi(d0,d1), K3));
            F2 = pk_add(F2, pk_cmuls(pk_sub(s0,s1), K6));
            F3 = pk_add(F3, pk_cmuls(pk_pi(d0,d1), K9));
        }
    }

    float rv[10];
    {
        // bin n = 256*p'' + c0, c0 = 16*(t&15) + (t>>4)
        const int c0i = ((t & 15) << 4) | (t >> 4);
        cf Q0 = pk_cmul(relu2(F0), w2c[c0i]);
        cf Q1 = pk_cmul(relu2(F1), w2c[256 + c0i]);
        cf Q2 = pk_cmul(relu2(F2), w2c[512 + c0i]);
        cf Q3 = pk_cmul(relu2(F3), w2c[768 + c0i]);

        cf s0 = pk_add(Q0,Q2), d0 = pk_sub(Q0,Q2);
        cf s1 = pk_add(Q1,Q3), d1 = pk_sub(Q1,Q3);
        cf G0 = pk_add(s0,s1);
        cf G1 = pk_mi(d0,d1);
        cf G2 = pk_sub(s0,s1);
        cf G3 = pk_pi(d0,d1);
        __sincosf(-TWO_PI * (float)c0i * (1.0f/1024.0f), &sn, &cs);
        cf wk = mkcf(cs, sn);
        cf r1 = wk;
        cf a1 = pk_cmul(G1, r1);
        cf r2 = pk_cmul(r1, wk);
        cf a2 = pk_cmul(G2, r2);
        cf r3 = pk_cmul(r2, wk);
        cf a3 = pk_cmul(G3, r3);
        cf r4 = pk_cmul(r3, wk);
        cf a4 = pk_cmul(G0, r4);              // k=4: (-i)^{4p''}=1 -> G0
        rv[0]=G0.x; rv[1]=G0.y; rv[2]=a1.x; rv[3]=a1.y; rv[4]=a2.x;
        rv[5]=a2.y; rv[6]=a3.x; rv[7]=a3.y; rv[8]=a4.x; rv[9]=a4.y;
    }

    // ---- reduce 256 threads -> 10 floats ----
    #pragma unroll
    for (int i = 0; i < 10; ++i) rv[i] = wred(rv[i]);
    const int lane = t & 63, wv = t >> 6;
    if (lane == 63) {
        #pragma unroll
        for (int i = 0; i < 10; ++i) sred[wv*10 + i] = rv[i];
    }
    __syncthreads();
    if (t < 10) {
        out[b*10 + t] = sred[t] + sred[10+t] + sred[20+t] + sred[30+t];
    }
}

extern "C" void kernel_launch(void* const* d_in, const int* in_sizes, int n_in,
                              void* d_out, int out_size, void* d_ws, size_t ws_size,
                              hipStream_t stream) {
    const float* x  = (const float*)d_in[0];
    const float* w1 = (const float*)d_in[1];
    const float* w2 = (const float*)d_in[2];
    float* out = (float*)d_out;
    fftmlp_bf<<<NBLK, 256, 0, stream>>>(x, w1, w2, out);
}

// Round 19
// 61.947 us; speedup vs baseline: 1.0110x; 1.0110x over previous
//
#include <hip/hip_runtime.h>

#define NBLK 8192
#define C1f 0.92387953251128674f
#define S1f 0.38268343236508978f
#define R2f 0.70710678118654752f
#define TWO_PI 6.28318530717958648f

// bank swizzle: XOR cf-index bits [3:1] with bits [6:4]. Involution on 0..4095.
#define SIDX(c) ((c) ^ ((((c) >> 4) & 7) << 1))

typedef float cf __attribute__((ext_vector_type(2)));
typedef float f4 __attribute__((ext_vector_type(4)));

__device__ __forceinline__ cf mkcf(float a, float b){ cf r; r.x = a; r.y = b; return r; }

// ---------- VOP3P packed-f32 helpers ----------
__device__ __forceinline__ cf pk_add(cf a, cf b){
    cf r; asm("v_pk_add_f32 %0, %1, %2" : "=v"(r) : "v"(a), "v"(b)); return r;
}
__device__ __forceinline__ cf pk_sub(cf a, cf b){
    cf r; asm("v_pk_add_f32 %0, %1, %2 neg_lo:[0,1] neg_hi:[0,1]" : "=v"(r) : "v"(a), "v"(b)); return r;
}
// a - i*b = (a.x + b.y, a.y - b.x)
__device__ __forceinline__ cf pk_mi(cf a, cf b){
    cf r; asm("v_pk_add_f32 %0, %1, %2 op_sel:[0,1] op_sel_hi:[1,0] neg_hi:[0,1]" : "=v"(r) : "v"(a), "v"(b)); return r;
}
// a + i*b = (a.x - b.y, a.y + b.x)
__device__ __forceinline__ cf pk_pi(cf a, cf b){
    cf r; asm("v_pk_add_f32 %0, %1, %2 op_sel:[0,1] op_sel_hi:[1,0] neg_lo:[0,1]" : "=v"(r) : "v"(a), "v"(b)); return r;
}
// (-i)*a = (a.y, -a.x)
__device__ __forceinline__ cf pk_ni(cf a){
    cf r; asm("v_pk_add_f32 %0, %1, 0 op_sel:[1,0] op_sel_hi:[0,0] neg_hi:[1,0]" : "=v"(r) : "v"(a)); return r;
}
// ReLU both halves (no v_pk_max_f32 on gfx950)
__device__ __forceinline__ cf relu2(cf a){
    return mkcf(fmaxf(a.x, 0.0f), fmaxf(a.y, 0.0f));
}
// complex multiply a*b, both runtime (VGPR)
__device__ __forceinline__ cf pk_cmul(cf a, cf b){
    cf t, r;
    asm("v_pk_mul_f32 %0, %1, %2 op_sel:[0,0] op_sel_hi:[0,1]"
        : "=v"(t) : "v"(a), "v"(b));
    asm("v_pk_fma_f32 %0, %1, %2, %3 op_sel:[1,1,0] op_sel_hi:[1,0,1] neg_lo:[1,0,0] neg_hi:[0,0,0]"
        : "=v"(r) : "v"(a), "v"(b), "v"(t));
    return r;
}
// complex multiply a*K, K compile-time -> SGPR pair
__device__ __forceinline__ cf pk_cmuls(cf a, cf b){
    cf t, r;
    asm("v_pk_mul_f32 %0, %1, %2 op_sel:[0,0] op_sel_hi:[0,1]"
        : "=v"(t) : "v"(a), "s"(b));
    asm("v_pk_fma_f32 %0, %1, %2, %3 op_sel:[1,1,0] op_sel_hi:[1,0,1] neg_lo:[1,0,0] neg_hi:[0,0,0]"
        : "=v"(r) : "v"(a), "s"(b), "v"(t));
    return r;
}

// in-register 16-point DFT (natural in/out), radix-4 DIF, packed ops, SGPR constants
__device__ __forceinline__ void fft16pk(cf v[16]) {
    const cf K1 = mkcf(C1f,-S1f), K2 = mkcf(R2f,-R2f), K3 = mkcf(S1f,-C1f),
             K6 = mkcf(-R2f,-R2f), K9 = mkcf(-C1f,S1f);
    cf y[16];
    #pragma unroll
    for (int j1 = 0; j1 < 4; ++j1) {
        cf a0 = v[j1], a1 = v[j1+4], a2 = v[j1+8], a3 = v[j1+12];
        cf s0 = pk_add(a0,a2), d0 = pk_sub(a0,a2);
        cf s1 = pk_add(a1,a3), d1 = pk_sub(a1,a3);
        cf b0 = pk_add(s0,s1);
        cf b1 = pk_mi(d0,d1);
        cf b2 = pk_sub(s0,s1);
        cf b3 = pk_pi(d0,d1);
        if (j1 == 0)      { y[0]=b0; y[4]=b1;              y[8]=b2;              y[12]=b3; }
        else if (j1 == 1) { y[1]=b0; y[5]=pk_cmuls(b1,K1); y[9]=pk_cmuls(b2,K2); y[13]=pk_cmuls(b3,K3); }
        else if (j1 == 2) { y[2]=b0; y[6]=pk_cmuls(b1,K2); y[10]=pk_ni(b2);      y[14]=pk_cmuls(b3,K6); }
        else              { y[3]=b0; y[7]=pk_cmuls(b1,K3); y[11]=pk_cmuls(b2,K6);y[15]=pk_cmuls(b3,K9); }
    }
    #pragma unroll
    for (int p1 = 0; p1 < 4; ++p1) {
        cf c0 = y[4*p1], c1v = y[4*p1+1], c2v = y[4*p1+2], c3v = y[4*p1+3];
        cf s0 = pk_add(c0,c2v), d0 = pk_sub(c0,c2v);
        cf s1 = pk_add(c1v,c3v), d1 = pk_sub(c1v,c3v);
        v[p1]    = pk_add(s0,s1);
        v[4+p1]  = pk_mi(d0,d1);
        v[8+p1]  = pk_sub(s0,s1);
        v[12+p1] = pk_pi(d0,d1);
    }
}

// 64-lane sum via DPP; valid in lane 63
__device__ __forceinline__ float wred(float x) {
    x += __int_as_float(__builtin_amdgcn_update_dpp(0, __float_as_int(x), 0x111, 0xf, 0xf, false));
    x += __int_as_float(__builtin_amdgcn_update_dpp(0, __float_as_int(x), 0x112, 0xf, 0xf, false));
    x += __int_as_float(__builtin_amdgcn_update_dpp(0, __float_as_int(x), 0x114, 0xf, 0xf, false));
    x += __int_as_float(__builtin_amdgcn_update_dpp(0, __float_as_int(x), 0x118, 0xf, 0xf, false));
    x += __int_as_float(__builtin_amdgcn_update_dpp(0, __float_as_int(x), 0x142, 0xa, 0xf, false));
    x += __int_as_float(__builtin_amdgcn_update_dpp(0, __float_as_int(x), 0x143, 0xc, 0xf, false));
    return x;
}

__global__ __launch_bounds__(256, 4)
void fftmlp_pks(const float* __restrict__ x, const float* __restrict__ w1,
                const float* __restrict__ w2, float* __restrict__ out) {
    __shared__ __align__(16) cf buf[4096];   // 32 KB work buffer
    __shared__ float sred[40];               // separate -> no alias barrier needed
    const int t = threadIdx.x;
    const int b = blockIdx.x;
    const cf* __restrict__ xr  = (const cf*)x + (size_t)b * 4096;
    const cf* __restrict__ w1c = (const cf*)w1;
    const cf* __restrict__ w2c = (const cf*)w2;
    float sn, cs;

    // ---- pass A: global x*w1 -> fft16 over stride-256 -> twiddle -> LDS ----
    {
        cf v[16];
        #pragma unroll
        for (int q = 0; q < 16; ++q)
            v[q] = pk_cmul(xr[t + 256*q], w1c[t + 256*q]);
        fft16pk(v);
        __sincosf(-TWO_PI * (float)t * (1.0f/4096.0f), &sn, &cs);
        cf w = mkcf(cs, sn);
        buf[SIDX(t)] = v[0];
        cf tw = w;
        #pragma unroll
        for (int p = 1; p < 16; ++p) {
            buf[SIDX(p*256 + t)] = pk_cmul(v[p], tw);
            tw = pk_cmul(tw, w);
        }
    }
    __syncthreads();

    // ---- pass B: within 256-blocks, stride 16, twiddle W_256^jp, in place ----
    {
        const int p    = t >> 4;
        const int jp   = t & 15;
        const int base = p*256 + jp;
        cf u[16];
        #pragma unroll
        for (int q = 0; q < 16; ++q) u[q] = buf[SIDX(base + 16*q)];
        fft16pk(u);
        __sincosf(-TWO_PI * (float)jp * (1.0f/256.0f), &sn, &cs);
        cf w = mkcf(cs, sn);
        buf[SIDX(base)] = u[0];
        cf tw = w;
        #pragma unroll
        for (int pp = 1; pp < 16; ++pp) {
            buf[SIDX(base + 16*pp)] = pk_cmul(u[pp], tw);
            tw = pk_cmul(tw, w);
        }
    }
    __syncthreads();

    // ---- final: incremental F accumulation (low register pressure) ----
    cf F0, F1, F2, F3;
    {
        const cf K1 = mkcf(C1f,-S1f), K2 = mkcf(R2f,-R2f), K3 = mkcf(S1f,-C1f),
                 K6 = mkcf(-R2f,-R2f), K9 = mkcf(-C1f,S1f);
        f4 q0 = *reinterpret_cast<const f4*>(&buf[SIDX(16*t + 0)]);
        f4 q2 = *reinterpret_cast<const f4*>(&buf[SIDX(16*t + 4)]);
        f4 q4 = *reinterpret_cast<const f4*>(&buf[SIDX(16*t + 8)]);
        f4 q6 = *reinterpret_cast<const f4*>(&buf[SIDX(16*t + 12)]);
        {   // bb = 0: z0, z4, z8, z12
            cf a0 = mkcf(q0.x,q0.y), a1 = mkcf(q2.x,q2.y), a2 = mkcf(q4.x,q4.y), a3 = mkcf(q6.x,q6.y);
            cf s0 = pk_add(a0,a2), d0 = pk_sub(a0,a2);
            cf s1 = pk_add(a1,a3), d1 = pk_sub(a1,a3);
            F0 = pk_add(s0,s1);
            F1 = pk_mi(d0,d1);
            F2 = pk_sub(s0,s1);
            F3 = pk_pi(d0,d1);
        }
        {   // bb = 1: multipliers 1,K1,K2,K3
            cf a0 = mkcf(q0.z,q0.w), a1 = mkcf(q2.z,q2.w), a2 = mkcf(q4.z,q4.w), a3 = mkcf(q6.z,q6.w);
            cf s0 = pk_add(a0,a2), d0 = pk_sub(a0,a2);
            cf s1 = pk_add(a1,a3), d1 = pk_sub(a1,a3);
            F0 = pk_add(F0, pk_add(s0,s1));
            F1 = pk_add(F1, pk_cmuls(pk_mi(d0,d1), K1));
            F2 = pk_add(F2, pk_cmuls(pk_sub(s0,s1), K2));
            F3 = pk_add(F3, pk_cmuls(pk_pi(d0,d1), K3));
        }
        f4 q1 = *reinterpret_cast<const f4*>(&buf[SIDX(16*t + 2)]);
        f4 q3 = *reinterpret_cast<const f4*>(&buf[SIDX(16*t + 6)]);
        f4 q5 = *reinterpret_cast<const f4*>(&buf[SIDX(16*t + 10)]);
        f4 q7 = *reinterpret_cast<const f4*>(&buf[SIDX(16*t + 14)]);
        {   // bb = 2: multipliers 1,K2,-i,K6
            cf a0 = mkcf(q1.x,q1.y), a1 = mkcf(q3.x,q3.y), a2 = mkcf(q5.x,q5.y), a3 = mkcf(q7.x,q7.y);
            cf s0 = pk_add(a0,a2), d0 = pk_sub(a0,a2);
            cf s1 = pk_add(a1,a3), d1 = pk_sub(a1,a3);
            F0 = pk_add(F0, pk_add(s0,s1));
            F1 = pk_add(F1, pk_cmuls(pk_mi(d0,d1), K2));
            F2 = pk_add(F2, pk_ni(pk_sub(s0,s1)));
            F3 = pk_add(F3, pk_cmuls(pk_pi(d0,d1), K6));
        }
        {   // bb = 3: multipliers 1,K3,K6,K9
            cf a0 = mkcf(q1.z,q1.w), a1 = mkcf(q3.z,q3.w), a2 = mkcf(q5.z,q5.w), a3 = mkcf(q7.z,q7.w);
            cf s0 = pk_add(a0,a2), d0 = pk_sub(a0,a2);
            cf s1 = pk_add(a1,a3), d1 = pk_sub(a1,a3);
            F0 = pk_add(F0, pk_add(s0,s1));
            F1 = pk_add(F1, pk_cmuls(pk_mi(d0,d1), K3));
            F2 = pk_add(F2, pk_cmuls(pk_sub(s0,s1), K6));
            F3 = pk_add(F3, pk_cmuls(pk_pi(d0,d1), K9));
        }
    }

    float rv[10];
    {
        // bin n = 256*p'' + c0, c0 = 16*(t&15) + (t>>4)
        const int c0i = ((t & 15) << 4) | (t >> 4);
        cf Q0 = pk_cmul(relu2(F0), w2c[c0i]);
        cf Q1 = pk_cmul(relu2(F1), w2c[256 + c0i]);
        cf Q2 = pk_cmul(relu2(F2), w2c[512 + c0i]);
        cf Q3 = pk_cmul(relu2(F3), w2c[768 + c0i]);

        cf s0 = pk_add(Q0,Q2), d0 = pk_sub(Q0,Q2);
        cf s1 = pk_add(Q1,Q3), d1 = pk_sub(Q1,Q3);
        cf G0 = pk_add(s0,s1);
        cf G1 = pk_mi(d0,d1);
        cf G2 = pk_sub(s0,s1);
        cf G3 = pk_pi(d0,d1);
        __sincosf(-TWO_PI * (float)c0i * (1.0f/1024.0f), &sn, &cs);
        cf wk = mkcf(cs, sn);
        cf r1 = wk;
        cf a1 = pk_cmul(G1, r1);
        cf r2 = pk_cmul(r1, wk);
        cf a2 = pk_cmul(G2, r2);
        cf r3 = pk_cmul(r2, wk);
        cf a3 = pk_cmul(G3, r3);
        cf r4 = pk_cmul(r3, wk);
        cf a4 = pk_cmul(G0, r4);              // k=4: (-i)^{4p''}=1 -> G0
        rv[0]=G0.x; rv[1]=G0.y; rv[2]=a1.x; rv[3]=a1.y; rv[4]=a2.x;
        rv[5]=a2.y; rv[6]=a3.x; rv[7]=a3.y; rv[8]=a4.x; rv[9]=a4.y;
    }

    // ---- reduce 256 threads -> 10 floats ----
    #pragma unroll
    for (int i = 0; i < 10; ++i) rv[i] = wred(rv[i]);
    const int lane = t & 63, wv = t >> 6;
    if (lane == 63) {
        #pragma unroll
        for (int i = 0; i < 10; ++i) sred[wv*10 + i] = rv[i];
    }
    __syncthreads();
    if (t < 10) {
        out[b*10 + t] = sred[t] + sred[10+t] + sred[20+t] + sred[30+t];
    }
}

extern "C" void kernel_launch(void* const* d_in, const int* in_sizes, int n_in,
                              void* d_out, int out_size, void* d_ws, size_t ws_size,
                              hipStream_t stream) {
    const float* x  = (const float*)d_in[0];
    const float* w1 = (const float*)d_in[1];
    const float* w2 = (const float*)d_in[2];
    float* out = (float*)d_out;
    fftmlp_pks<<<NBLK, 256, 0, stream>>>(x, w1, w2, out);
}